// Round 1
// baseline (57.388 us; speedup 1.0000x reference)
//
#include <hip/hip_runtime.h>

// Problem constants (fixed by the reference)
constexpr int Bsz  = 512;
constexpr int Nn   = 256;   // agents
constexpr int FINc = 32;
constexpr int H1c  = 16;
constexpr int Gc   = 8;
constexpr int FOUTc= 16;
constexpr int Kc   = 3;
constexpr int ACTc = 5;

// One block per batch element. 256 threads = 4 waves. 2 blocks/CU.
__global__ __launch_bounds__(256, 2)
void cpn_kernel(const float* __restrict__ x,  const float* __restrict__ S,
                const float* __restrict__ W1, const float* __restrict__ b1,
                const float* __restrict__ W2, const float* __restrict__ b2,
                const float* __restrict__ Hgf,const float* __restrict__ bgf,
                const float* __restrict__ Wa, const float* __restrict__ ba,
                float* __restrict__ out)
{
    const int b    = blockIdx.x;
    const int tid  = threadIdx.x;
    const int wid  = tid >> 6;
    const int lane = tid & 63;
    const int n    = tid;            // this thread's agent for phases A/C

    __shared__ __align__(16) float zA[Nn][Gc];        // z0, n-major (broadcast-friendly)
    __shared__ __align__(16) float zB[Nn][Gc];        // z1, n-major
    __shared__ __align__(16) float zpart[4][Gc][Nn];  // per-wave partial sums

    // ---------------- Phase A: compress MLP (thread = agent n) ----------------
    float xr[FINc];
    {
        const float4* xp = reinterpret_cast<const float4*>(x + ((size_t)b * Nn + n) * FINc);
        #pragma unroll
        for (int i = 0; i < FINc / 4; ++i) {
            float4 v = xp[i];
            xr[4*i+0] = v.x; xr[4*i+1] = v.y; xr[4*i+2] = v.z; xr[4*i+3] = v.w;
        }
    }
    float h1v[H1c];
    #pragma unroll
    for (int h = 0; h < H1c; ++h) {
        float a = b1[h];
        #pragma unroll
        for (int f = 0; f < FINc; ++f) a = fmaf(W1[h*FINc + f], xr[f], a);
        h1v[h] = fmaxf(a, 0.0f);
    }
    float z0r[Gc];
    #pragma unroll
    for (int g = 0; g < Gc; ++g) {
        float a = b2[g];
        #pragma unroll
        for (int h = 0; h < H1c; ++h) a = fmaf(W2[g*H1c + h], h1v[h], a);
        z0r[g] = fmaxf(a, 0.0f);
        zA[n][g] = z0r[g];
    }
    __syncthreads();

    // ---------------- S passes: z_k = z_{k-1} @ S ----------------
    // wave `wid` owns rows n in [64*wid, 64*wid+64); lane owns columns 4*lane..4*lane+3.
    float z1r[Gc], z2r[Gc];

    auto spass = [&](const float (*zsrc)[Gc], float* zred) {
        float acc[Gc][4];
        #pragma unroll
        for (int g = 0; g < Gc; ++g) {
            #pragma unroll
            for (int j = 0; j < 4; ++j) acc[g][j] = 0.0f;
        }
        const float* srow = S + ((size_t)b * Nn + wid * 64) * Nn + 4 * lane;
        #pragma unroll 8
        for (int i = 0; i < 64; ++i) {
            const float4 sv = *reinterpret_cast<const float4*>(srow);   // coalesced 16B/lane
            srow += Nn;
            const int nn = wid * 64 + i;
            const float4 za = *reinterpret_cast<const float4*>(&zsrc[nn][0]); // LDS broadcast
            const float4 zb = *reinterpret_cast<const float4*>(&zsrc[nn][4]);
            const float zg[Gc] = {za.x, za.y, za.z, za.w, zb.x, zb.y, zb.z, zb.w};
            #pragma unroll
            for (int g = 0; g < Gc; ++g) {
                acc[g][0] = fmaf(zg[g], sv.x, acc[g][0]);
                acc[g][1] = fmaf(zg[g], sv.y, acc[g][1]);
                acc[g][2] = fmaf(zg[g], sv.z, acc[g][2]);
                acc[g][3] = fmaf(zg[g], sv.w, acc[g][3]);
            }
        }
        #pragma unroll
        for (int g = 0; g < Gc; ++g) {                 // conflict-free contiguous b128 writes
            *reinterpret_cast<float4*>(&zpart[wid][g][4*lane]) =
                make_float4(acc[g][0], acc[g][1], acc[g][2], acc[g][3]);
        }
        __syncthreads();
        #pragma unroll
        for (int g = 0; g < Gc; ++g) {                 // conflict-free stride-1 reads
            zred[g] = (zpart[0][g][n] + zpart[1][g][n]) + (zpart[2][g][n] + zpart[3][g][n]);
        }
    };

    spass(zA, z1r);
    #pragma unroll
    for (int g = 0; g < Gc; ++g) zB[n][g] = z1r[g];    // publish z1 for pass 2
    __syncthreads();                                    // also guards zpart reuse
    spass(zB, z2r);

    // ---------------- Phase C: graph filter + action head ----------------
    float y[FOUTc];
    #pragma unroll
    for (int f = 0; f < FOUTc; ++f) y[f] = bgf[f];
    #pragma unroll
    for (int g = 0; g < Gc; ++g) {
        const float zv = z0r[g];
        #pragma unroll
        for (int f = 0; f < FOUTc; ++f) y[f] = fmaf(Hgf[f*(Kc*Gc) + 0*Gc + g], zv, y[f]);
    }
    #pragma unroll
    for (int g = 0; g < Gc; ++g) {
        const float zv = z1r[g];
        #pragma unroll
        for (int f = 0; f < FOUTc; ++f) y[f] = fmaf(Hgf[f*(Kc*Gc) + 1*Gc + g], zv, y[f]);
    }
    #pragma unroll
    for (int g = 0; g < Gc; ++g) {
        const float zv = z2r[g];
        #pragma unroll
        for (int f = 0; f < FOUTc; ++f) y[f] = fmaf(Hgf[f*(Kc*Gc) + 2*Gc + g], zv, y[f]);
    }
    #pragma unroll
    for (int f = 0; f < FOUTc; ++f) y[f] = fmaxf(y[f], 0.0f);

    float* op = out + ((size_t)b * Nn + n) * ACTc;
    #pragma unroll
    for (int a = 0; a < ACTc; ++a) {
        float acc = ba[a];
        #pragma unroll
        for (int f = 0; f < FOUTc; ++f) acc = fmaf(Wa[a*FOUTc + f], y[f], acc);
        op[a] = acc;
    }
}

extern "C" void kernel_launch(void* const* d_in, const int* in_sizes, int n_in,
                              void* d_out, int out_size, void* d_ws, size_t ws_size,
                              hipStream_t stream) {
    const float* x   = (const float*)d_in[0];
    const float* S   = (const float*)d_in[1];
    const float* W1  = (const float*)d_in[2];
    const float* b1  = (const float*)d_in[3];
    const float* W2  = (const float*)d_in[4];
    const float* b2  = (const float*)d_in[5];
    const float* Hgf = (const float*)d_in[6];
    const float* bgf = (const float*)d_in[7];
    const float* Wa  = (const float*)d_in[8];
    const float* ba  = (const float*)d_in[9];

    cpn_kernel<<<dim3(Bsz), dim3(Nn), 0, stream>>>(
        x, S, W1, b1, W2, b2, Hgf, bgf, Wa, ba, (float*)d_out);
}

// Round 2
// 52.215 us; speedup vs baseline: 1.0991x; 1.0991x over previous
//
#include <hip/hip_runtime.h>

// Problem constants (fixed by the reference)
constexpr int Bsz  = 512;
constexpr int Nn   = 256;   // agents
constexpr int FINc = 32;
constexpr int H1c  = 16;
constexpr int Gc   = 8;
constexpr int FOUTc= 16;
constexpr int Kc   = 3;
constexpr int ACTc = 5;

// One block per batch element. 512 threads = 8 waves -> 16 waves/CU (2 blocks/CU).
__global__ __launch_bounds__(512, 4)
void cpn_kernel(const float* __restrict__ x,  const float* __restrict__ S,
                const float* __restrict__ W1, const float* __restrict__ b1,
                const float* __restrict__ W2, const float* __restrict__ b2,
                const float* __restrict__ Hgf,const float* __restrict__ bgf,
                const float* __restrict__ Wa, const float* __restrict__ ba,
                float* __restrict__ out)
{
    const int b    = blockIdx.x;
    const int tid  = threadIdx.x;
    const int wid  = tid >> 6;
    const int lane = tid & 63;
    const int rg   = wid >> 1;       // row-group 0..3   (rows [64*rg, 64*rg+64))
    const int cg   = wid & 1;        // col-group 0..1   (cols [128*cg, 128*cg+128))
    const int n    = tid;            // agent index for phases A/C (tid < 256 only)

    __shared__ __align__(16) float zA[Nn][Gc];        // z0, n-major (broadcast-friendly)
    __shared__ __align__(16) float zB[Nn][Gc];        // z1, n-major
    __shared__ __align__(16) float zpart[4][Gc][Nn];  // per-row-group partial sums

    // ---------------- Phase A: compress MLP (thread = agent n, tid<256) ----------------
    float z0r[Gc];
    if (tid < Nn) {
        float xr[FINc];
        const float4* xp = reinterpret_cast<const float4*>(x + ((size_t)b * Nn + n) * FINc);
        #pragma unroll
        for (int i = 0; i < FINc / 4; ++i) {
            float4 v = xp[i];
            xr[4*i+0] = v.x; xr[4*i+1] = v.y; xr[4*i+2] = v.z; xr[4*i+3] = v.w;
        }
        float h1v[H1c];
        #pragma unroll
        for (int h = 0; h < H1c; ++h) {
            float a = b1[h];
            #pragma unroll
            for (int f = 0; f < FINc; ++f) a = fmaf(W1[h*FINc + f], xr[f], a);
            h1v[h] = fmaxf(a, 0.0f);
        }
        #pragma unroll
        for (int g = 0; g < Gc; ++g) {
            float a = b2[g];
            #pragma unroll
            for (int h = 0; h < H1c; ++h) a = fmaf(W2[g*H1c + h], h1v[h], a);
            z0r[g] = fmaxf(a, 0.0f);
            zA[n][g] = z0r[g];
        }
    }
    __syncthreads();

    // ---------------- S passes: z_k = z_{k-1} @ S ----------------
    // wave (rg,cg): rows [64*rg, 64*rg+64), lane owns columns 128*cg + 2*lane .. +1.
    float z1r[Gc], z2r[Gc];

    auto spass = [&](const float (*zsrc)[Gc], float* zred) {
        float acc[Gc][2];
        #pragma unroll
        for (int g = 0; g < Gc; ++g) { acc[g][0] = 0.0f; acc[g][1] = 0.0f; }

        const float* srow = S + ((size_t)b * Nn + rg * 64) * Nn + cg * 128 + 2 * lane;
        #pragma unroll 16
        for (int i = 0; i < 64; ++i) {
            const float2 sv = *reinterpret_cast<const float2*>(srow);   // coalesced 8B/lane
            srow += Nn;
            const int nn = rg * 64 + i;
            const float4 za = *reinterpret_cast<const float4*>(&zsrc[nn][0]); // LDS broadcast
            const float4 zb = *reinterpret_cast<const float4*>(&zsrc[nn][4]);
            const float zg[Gc] = {za.x, za.y, za.z, za.w, zb.x, zb.y, zb.z, zb.w};
            #pragma unroll
            for (int g = 0; g < Gc; ++g) {
                acc[g][0] = fmaf(zg[g], sv.x, acc[g][0]);
                acc[g][1] = fmaf(zg[g], sv.y, acc[g][1]);
            }
        }
        #pragma unroll
        for (int g = 0; g < Gc; ++g) {                 // disjoint float2 stores, conflict-free
            *reinterpret_cast<float2*>(&zpart[rg][g][cg * 128 + 2 * lane]) =
                make_float2(acc[g][0], acc[g][1]);
        }
        __syncthreads();
        if (tid < Nn) {
            #pragma unroll
            for (int g = 0; g < Gc; ++g)               // stride-1 reads, conflict-free
                zred[g] = (zpart[0][g][n] + zpart[1][g][n]) + (zpart[2][g][n] + zpart[3][g][n]);
        }
    };

    spass(zA, z1r);
    if (tid < Nn) {
        #pragma unroll
        for (int g = 0; g < Gc; ++g) zB[n][g] = z1r[g];    // publish z1 for pass 2
    }
    __syncthreads();                                        // guards zB publish + zpart reuse
    spass(zB, z2r);

    // ---------------- Phase C: graph filter + action head (tid<256) ----------------
    if (tid < Nn) {
        float y[FOUTc];
        #pragma unroll
        for (int f = 0; f < FOUTc; ++f) y[f] = bgf[f];
        #pragma unroll
        for (int g = 0; g < Gc; ++g) {
            const float zv = z0r[g];
            #pragma unroll
            for (int f = 0; f < FOUTc; ++f) y[f] = fmaf(Hgf[f*(Kc*Gc) + 0*Gc + g], zv, y[f]);
        }
        #pragma unroll
        for (int g = 0; g < Gc; ++g) {
            const float zv = z1r[g];
            #pragma unroll
            for (int f = 0; f < FOUTc; ++f) y[f] = fmaf(Hgf[f*(Kc*Gc) + 1*Gc + g], zv, y[f]);
        }
        #pragma unroll
        for (int g = 0; g < Gc; ++g) {
            const float zv = z2r[g];
            #pragma unroll
            for (int f = 0; f < FOUTc; ++f) y[f] = fmaf(Hgf[f*(Kc*Gc) + 2*Gc + g], zv, y[f]);
        }
        #pragma unroll
        for (int f = 0; f < FOUTc; ++f) y[f] = fmaxf(y[f], 0.0f);

        float* op = out + ((size_t)b * Nn + n) * ACTc;
        #pragma unroll
        for (int a = 0; a < ACTc; ++a) {
            float acc = ba[a];
            #pragma unroll
            for (int f = 0; f < FOUTc; ++f) acc = fmaf(Wa[a*FOUTc + f], y[f], acc);
            op[a] = acc;
        }
    }
}

extern "C" void kernel_launch(void* const* d_in, const int* in_sizes, int n_in,
                              void* d_out, int out_size, void* d_ws, size_t ws_size,
                              hipStream_t stream) {
    const float* x   = (const float*)d_in[0];
    const float* S   = (const float*)d_in[1];
    const float* W1  = (const float*)d_in[2];
    const float* b1  = (const float*)d_in[3];
    const float* W2  = (const float*)d_in[4];
    const float* b2  = (const float*)d_in[5];
    const float* Hgf = (const float*)d_in[6];
    const float* bgf = (const float*)d_in[7];
    const float* Wa  = (const float*)d_in[8];
    const float* ba  = (const float*)d_in[9];

    cpn_kernel<<<dim3(Bsz), dim3(512), 0, stream>>>(
        x, S, W1, b1, W2, b2, Hgf, bgf, Wa, ba, (float*)d_out);
}